// Round 18
// baseline (136.035 us; speedup 1.0000x reference)
//
#include <hip/hip_runtime.h>
#include <stdint.h>

#define B_SZ 2
#define T_SEQ 2048
#define D_MODEL 1024
#define NHEADS 16
#define HDIM 64
#define QKV_P (3 * D_MODEL) /* 3072 */

typedef unsigned short u16;
typedef uint32_t u32;
typedef __attribute__((ext_vector_type(4))) float f32x4;
typedef __attribute__((ext_vector_type(8))) short s16x8;
typedef __attribute__((ext_vector_type(4))) short s16x4;

__device__ __forceinline__ u16 f2bf(float f) {
  union { float f; uint32_t u; } v; v.f = f;
  uint32_t r = v.u + 0x7fffu + ((v.u >> 16) & 1u);
  return (u16)(r >> 16);
}

__device__ __forceinline__ float fastexp2(float x) {
  float r;
  asm volatile("v_exp_f32 %0, %1" : "=v"(r) : "v"(x));
  return r;
}

__device__ __forceinline__ u32 cvtpk(float lo, float hi) {
  u32 r;
  asm volatile("v_cvt_pk_bf16_f32 %0, %1, %2" : "=v"(r) : "v"(lo), "v"(hi));
  return r;
}

__device__ __forceinline__ void async16(const void* g, void* l) {
  __builtin_amdgcn_global_load_lds((const __attribute__((address_space(1))) void*)g,
                                   (__attribute__((address_space(3))) void*)l,
                                   16, 0, 0);
}

// raw barrier: does NOT drain vmcnt (unlike __syncthreads)
__device__ __forceinline__ void rawbar() {
  __builtin_amdgcn_s_barrier();
  __builtin_amdgcn_sched_barrier(0);
}

// ---------------- merged prep: x->bf16, w_qkv^T->bf16, w_proj^T->bf16 ----------------
__global__ __launch_bounds__(256) void prep(const float* __restrict__ x,
                                            const float* __restrict__ wq,
                                            const float* __restrict__ wp,
                                            u16* __restrict__ xb,
                                            u16* __restrict__ wqkvT,
                                            u16* __restrict__ wprojT) {
  const int bid = blockIdx.x, tid = threadIdx.x;
  if (bid < 4096) {
    int i = bid * 256 + tid;
    float4 v = ((const float4*)x)[i];
    ushort4 o;
    o.x = f2bf(v.x); o.y = f2bf(v.y); o.z = f2bf(v.z); o.w = f2bf(v.w);
    ((ushort4*)xb)[i] = o;
    return;
  }
  __shared__ float tile[32][33];
  const float* in; u16* outp; int C, bx, by;
  if (bid < 4096 + 3072) {
    int bb = bid - 4096; in = wq; outp = wqkvT; C = 3072; bx = bb % 96; by = bb / 96;
  } else {
    int bb = bid - 7168; in = wp; outp = wprojT; C = 1024; bx = bb % 32; by = bb / 32;
  }
  const int tx = tid & 31, ty = tid >> 5;
  const int c0 = bx * 32, r0 = by * 32;
#pragma unroll
  for (int i = 0; i < 4; i++)
    tile[ty + i * 8][tx] = in[(size_t)(r0 + ty + i * 8) * C + c0 + tx];
  __syncthreads();
#pragma unroll
  for (int i = 0; i < 4; i++)
    outp[(size_t)(c0 + ty + i * 8) * D_MODEL + r0 + tx] = f2bf(tile[tx][ty + i * 8]);
}

// ---------------- 128x128-tile BK=64 GEMM, 4-phase/K-tile interleave ----------------
// Per phase: stage ONE half-tile (2 loads) of tile t+1; phase 0 additionally
// vmcnt(2) (exactly tile t drained, new loads stay in flight) + barrier; then
// ds_read one A-frag pair and run a setprio-wrapped 8-MFMA cluster; barrier.
// Loads span all 4 phases (never vmcnt(0) mid-loop). T2 swizzle both sides.
// VFUSE: bn>=16 (V third, NBN=24) writes transposed into vT.
template <int F32OUT, int VFUSE, int NBN>
__global__ __launch_bounds__(256, 2) void gemm128(const u16* __restrict__ A,
                                                  const u16* __restrict__ BT,
                                                  void* __restrict__ Cout,
                                                  u16* __restrict__ vTout,
                                                  int N) {
  __shared__ u16 As[2][128 * 64];
  __shared__ u16 Bs[2][128 * 64];
  const int tid = threadIdx.x;
  const int lane = tid & 63, w = tid >> 6;
  const int l15 = lane & 15, g = lane >> 4;
  const int wr = w >> 1, wc = w & 1;
  const int id = blockIdx.x;
  const int cid = id >> 3;
  const int bm = (id & 7) * 4 + cid / NBN;
  const int bn = cid % NBN;
  const int K = 1024;
  const u16* Ab = A + (size_t)bm * 128 * K;
  const u16* Bb = BT + (size_t)bn * 128 * K;
  f32x4 acc[4][4];
#pragma unroll
  for (int i = 0; i < 4; i++)
#pragma unroll
    for (int j = 0; j < 4; j++) acc[i][j] = (f32x4){0.f, 0.f, 0.f, 0.f};

  // stage half-tile h (64 rows x 64 cols = 8KB = 2 chunks/thread)
#define LDH(dstbase, srcb, h_, kt_)                                           \
  do {                                                                        \
    _Pragma("unroll") for (int i_ = 0; i_ < 2; i_++) {                        \
      int o_ = (h_)*8192 + (tid + i_ * 256) * 16;                             \
      int lo_ = o_ ^ (((o_ >> 7) & 7) << 4);                                  \
      async16((srcb) + (size_t)(lo_ >> 7) * K + (kt_) + ((lo_ & 127) >> 1),   \
              (char*)(dstbase) + o_);                                         \
    }                                                                         \
  } while (0)

  // one phase: read A-frag pair for m-frag i_, 8 MFMA, barrier
#define PHASE(i_)                                                             \
  {                                                                           \
    int r_ = wr * 64 + (i_)*16 + l15;                                         \
    s16x8 a0 = *(const s16x8*)((const char*)As[cur] +                         \
                               ((r_ * 128 + g * 16) ^ ((r_ & 7) << 4)));      \
    s16x8 a1 = *(const s16x8*)((const char*)As[cur] +                         \
                               ((r_ * 128 + 64 + g * 16) ^ ((r_ & 7) << 4))); \
    __builtin_amdgcn_s_setprio(1);                                            \
    _Pragma("unroll") for (int jn = 0; jn < 4; jn++) {                        \
      acc[i_][jn] =                                                           \
          __builtin_amdgcn_mfma_f32_16x16x32_bf16(a0, bf[jn][0], acc[i_][jn], 0, 0, 0); \
      acc[i_][jn] =                                                           \
          __builtin_amdgcn_mfma_f32_16x16x32_bf16(a1, bf[jn][1], acc[i_][jn], 0, 0, 0); \
    }                                                                         \
    __builtin_amdgcn_s_setprio(0);                                            \
    rawbar();                                                                 \
  }

  // prologue: all 4 halves of tile 0
  LDH(As[0], Ab, 0, 0);
  LDH(As[0], Ab, 1, 0);
  LDH(Bs[0], Bb, 0, 0);
  LDH(Bs[0], Bb, 1, 0);
  int cur = 0;
  for (int t = 0; t < 16; t++) {
    const bool pf = (t < 15);
    const int ktn = (t + 1) * 64;
    // ---- phase 0: stage B0(t+1); drain tile t exactly; read all B-frags; MFMA i=0
    if (pf) {
      LDH(Bs[cur ^ 1], Bb, 0, ktn);
      asm volatile("s_waitcnt vmcnt(2)" ::: "memory");
    } else {
      asm volatile("s_waitcnt vmcnt(0)" ::: "memory");
    }
    rawbar();
    s16x8 bf[4][2];
#pragma unroll
    for (int jn = 0; jn < 4; jn++) {
      int n_ = wc * 64 + jn * 16 + l15;
      bf[jn][0] = *(const s16x8*)((const char*)Bs[cur] +
                                  ((n_ * 128 + g * 16) ^ ((n_ & 7) << 4)));
      bf[jn][1] = *(const s16x8*)((const char*)Bs[cur] +
                                  ((n_ * 128 + 64 + g * 16) ^ ((n_ & 7) << 4)));
    }
    PHASE(0);
    // ---- phase 1: stage B1(t+1); MFMA i=1
    if (pf) LDH(Bs[cur ^ 1], Bb, 1, ktn);
    PHASE(1);
    // ---- phase 2: stage A0(t+1); MFMA i=2
    if (pf) LDH(As[cur ^ 1], Ab, 0, ktn);
    PHASE(2);
    // ---- phase 3: stage A1(t+1); MFMA i=3
    if (pf) LDH(As[cur ^ 1], Ab, 1, ktn);
    PHASE(3);
    cur ^= 1;
  }

  if (VFUSE && bn >= 16) {
#pragma unroll
    for (int i = 0; i < 4; i++) {
      const int m = bm * 128 + wr * 64 + i * 16 + g * 4;
      const int bloc = m >> 11;
      const int tl = m & 2047;
#pragma unroll
      for (int jn = 0; jn < 4; jn++) {
        const int hh = bn * 128 + wc * 64 + jn * 16 + l15 - 2048;
        uint2 pk;
        pk.x = cvtpk(acc[i][jn][0], acc[i][jn][1]);
        pk.y = cvtpk(acc[i][jn][2], acc[i][jn][3]);
        *(uint2*)&vTout[(size_t)(bloc * 1024 + hh) * T_SEQ + tl] = pk;
      }
    }
    return;
  }
#pragma unroll
  for (int i = 0; i < 4; i++) {
    const int row0 = bm * 128 + wr * 64 + i * 16 + g * 4;
#pragma unroll
    for (int jn = 0; jn < 4; jn++) {
      const int col = bn * 128 + wc * 64 + jn * 16 + l15;
#pragma unroll
      for (int r = 0; r < 4; r++) {
        if (F32OUT)
          ((float*)Cout)[(size_t)(row0 + r) * N + col] = acc[i][jn][r];
        else
          ((u16*)Cout)[(size_t)(row0 + r) * N + col] = f2bf(acc[i][jn][r]);
      }
    }
  }
}

// ---------------- causal flash attention v12 (unchanged from r15) ----------
__global__ __launch_bounds__(256, 4) void flash_attn(const u16* __restrict__ qkv,
                                                     const u16* __restrict__ vT,
                                                     u16* __restrict__ attn) {
  __shared__ u16 Ks[2][64 * 64];  // [key][hd], XOR-swizzled
  __shared__ u16 Vs[2][64 * 64];  // [hd][key], XOR-swizzled
  const int tid = threadIdx.x;
  const int lane = tid & 63, w = tid >> 6;
  const int l15 = lane & 15, g = lane >> 4;
  const int id = blockIdx.x;
  const int bh = ((id & 7) << 2) | ((id >> 3) & 3);  // 4 heads per XCD
  const int j = (id >> 5) & 7, k4 = (id >> 8) & 3;   // balanced strip map
  const int qs = (k4 == 0) ? (31 - j) : (k4 == 1) ? (16 + j) : (k4 == 2) ? (15 - j) : j;
  const int b = bh >> 4, h = bh & 15;

  const size_t qrow = (size_t)(b * T_SEQ + qs * 64 + w * 16 + l15);
  s16x8 qf[2];
  qf[0] = *(const s16x8*)(qkv + qrow * QKV_P + h * HDIM + 0 * 32 + g * 8);
  qf[1] = *(const s16x8*)(qkv + qrow * QKV_P + h * HDIM + 1 * 32 + g * 8);

  f32x4 O[4];
#pragma unroll
  for (int t = 0; t < 4; t++) O[t] = (f32x4){0.f, 0.f, 0.f, 0.f};
  f32x4 sumacc = (f32x4){0.f, 0.f, 0.f, 0.f};  // l via ones-row PV MFMA
  float m_s = -1e30f;
  const int qrl = w * 16 + l15;
  const float sc = 0.18033688011112042f;  // (1/sqrt(64)) * log2(e)
  const s16x4 onesf = {(short)0x3F80, (short)0x3F80, (short)0x3F80, (short)0x3F80};

#define STAGE(buf, kvt_)                                                                     \
  do {                                                                                       \
    _Pragma("unroll") for (int i_ = 0; i_ < 2; i_++) {                                       \
      int o_ = (tid + i_ * 256) * 16;                                                        \
      int lo_ = o_ ^ (((o_ >> 7) & 7) << 4);                                                 \
      int row_ = lo_ >> 7;                                                                   \
      int byt_ = lo_ & 127;                                                                  \
      async16(qkv + (size_t)(b * T_SEQ + (kvt_) * 64 + row_) * QKV_P + D_MODEL + h * HDIM +  \
                  (byt_ >> 1),                                                               \
              (char*)Ks[buf] + o_);                                                          \
      async16(vT + (size_t)(bh * HDIM + row_) * T_SEQ + (kvt_) * 64 + (byt_ >> 1),           \
              (char*)Vs[buf] + o_);                                                          \
    }                                                                                        \
  } while (0)

  STAGE(0, 0);
  int cur = 0;
  const int nt = qs + 1;
  for (int kvt = 0; kvt < nt; ++kvt) {
    if (kvt < qs) {
      STAGE(cur ^ 1, kvt + 1);
      asm volatile("s_waitcnt vmcnt(4)" ::: "memory");
    } else {
      asm volatile("s_waitcnt vmcnt(0)" ::: "memory");
    }
    rawbar();

    f32x4 S[4];
#pragma unroll
    for (int t16 = 0; t16 < 4; t16++) S[t16] = (f32x4){0.f, 0.f, 0.f, 0.f};
#pragma unroll
    for (int t16 = 0; t16 < 4; t16++)
#pragma unroll
      for (int kk = 0; kk < 2; kk++) {
        int key = t16 * 16 + l15;
        int bp = (key * 128 + kk * 64 + g * 16) ^ ((key & 7) << 4);
        s16x8 kf = *(const s16x8*)((const char*)Ks[cur] + bp);
        S[t16] = __builtin_amdgcn_mfma_f32_16x16x32_bf16(kf, qf[kk], S[t16], 0, 0, 0);
      }

    if (kvt == qs) {  // causal mask (raw units)
#pragma unroll
      for (int t16 = 0; t16 < 4; t16++)
#pragma unroll
        for (int r = 0; r < 4; r++)
          if (t16 * 16 + g * 4 + r > qrl) S[t16][r] = -3e38f;
    }
    // per-lane PARTIAL max (this lane's 16 of the query's 64 keys) — no shfl
    float pmx = fmaxf(fmaxf(fmaxf(S[0][0], S[0][1]), fmaxf(S[0][2], S[0][3])),
                      fmaxf(fmaxf(S[1][0], S[1][1]), fmaxf(S[1][2], S[1][3])));
    pmx = fmaxf(pmx, fmaxf(fmaxf(fmaxf(S[2][0], S[2][1]), fmaxf(S[2][2], S[2][3])),
                           fmaxf(fmaxf(S[3][0], S[3][1]), fmaxf(S[3][2], S[3][3]))));
    // __all over wave == testing full row max for every query in this wave
    if (!__all(pmx - m_s <= 40.f)) {  // rare rescale path
      float mx = fmaxf(pmx, __shfl_xor(pmx, 16));
      mx = fmaxf(mx, __shfl_xor(mx, 32));
      const float mnew = fmaxf(m_s, mx);
      const float alpha = fastexp2((m_s - mnew) * sc);
      m_s = mnew;
      sumacc[0] *= alpha; sumacc[1] *= alpha; sumacc[2] *= alpha; sumacc[3] *= alpha;
#pragma unroll
      for (int t = 0; t < 4; t++)
#pragma unroll
        for (int r = 0; r < 4; r++) O[t][r] *= alpha;
    }
    const float msc = m_s * sc;
    float p[16];
#pragma unroll
    for (int t16 = 0; t16 < 4; t16++)
#pragma unroll
      for (int r = 0; r < 4; r++) p[t16 * 4 + r] = fastexp2(fmaf(S[t16][r], sc, -msc));

    // pack + PV (16x16x16: B-frag k = g*4+j == S/P C-layout) + ones-row sum MFMA
#pragma unroll
    for (int t16 = 0; t16 < 4; t16++) {
      union { u32 u[2]; s16x4 v; } pbv;
      pbv.u[0] = cvtpk(p[t16 * 4 + 0], p[t16 * 4 + 1]);
      pbv.u[1] = cvtpk(p[t16 * 4 + 2], p[t16 * 4 + 3]);
      sumacc = __builtin_amdgcn_mfma_f32_16x16x16bf16_1k(onesf, pbv.v, sumacc, 0, 0, 0);
#pragma unroll
      for (int t = 0; t < 4; t++) {
        int hd = t * 16 + l15;
        int bp = (hd * 128 + t16 * 32 + g * 8) ^ ((hd & 7) << 4);
        s16x4 vf = *(const s16x4*)((const char*)Vs[cur] + bp);
        O[t] = __builtin_amdgcn_mfma_f32_16x16x16bf16_1k(vf, pbv.v, O[t], 0, 0, 0);
      }
    }
    rawbar();
    cur ^= 1;
  }

  const float inv = 1.0f / sumacc[0];
  const size_t row = (size_t)(b * T_SEQ + qs * 64 + w * 16 + l15);
#pragma unroll
  for (int t = 0; t < 4; t++)
#pragma unroll
    for (int pr = 0; pr < 2; pr++) {
      u32 pk = cvtpk(O[t][pr * 2 + 0] * inv, O[t][pr * 2 + 1] * inv);
      *(u32*)&attn[row * D_MODEL + h * HDIM + t * 16 + g * 4 + pr * 2] = pk;
    }
}

extern "C" void kernel_launch(void* const* d_in, const int* in_sizes, int n_in,
                              void* d_out, int out_size, void* d_ws, size_t ws_size,
                              hipStream_t stream) {
  const float* x = (const float*)d_in[0];
  const float* w_qkv = (const float*)d_in[1];
  const float* w_proj = (const float*)d_in[2];
  float* out = (float*)d_out;
  char* ws = (char*)d_ws;
  const size_t MB = (size_t)1 << 20;
  if (ws_size < 56 * MB) return;  // need 56 MB scratch
  u16* xb = (u16*)(ws + 0);            // 8 MB  [4096][1024] bf16
  u16* wqkvT = (u16*)(ws + 8 * MB);    // 6 MB  [3072][1024] bf16
  u16* wprojT = (u16*)(ws + 14 * MB);  // 2 MB  [1024][1024] bf16
  u16* qkv = (u16*)(ws + 16 * MB);     // 24 MB [4096][3072] bf16 (V third unused)
  u16* vT = (u16*)(ws + 40 * MB);      // 8 MB  [2*1024][2048] bf16
  u16* attn = (u16*)(ws + 48 * MB);    // 8 MB  [4096][1024] bf16

  prep<<<8192, 256, 0, stream>>>(x, w_qkv, w_proj, xb, wqkvT, wprojT);
  gemm128<0, 1, 24><<<768, 256, 0, stream>>>(xb, wqkvT, qkv, vT, QKV_P);
  flash_attn<<<1024, 256, 0, stream>>>(qkv, vT, attn);
  gemm128<1, 0, 8><<<256, 256, 0, stream>>>(attn, wprojT, out, nullptr, D_MODEL);
}

// Round 19
// 102.718 us; speedup vs baseline: 1.3244x; 1.3244x over previous
//
#include <hip/hip_runtime.h>
#include <stdint.h>

#define B_SZ 2
#define T_SEQ 2048
#define D_MODEL 1024
#define NHEADS 16
#define HDIM 64
#define QKV_P (3 * D_MODEL) /* 3072 */

typedef unsigned short u16;
typedef uint32_t u32;
typedef __attribute__((ext_vector_type(4))) float f32x4;
typedef __attribute__((ext_vector_type(8))) short s16x8;
typedef __attribute__((ext_vector_type(4))) short s16x4;

__device__ __forceinline__ u16 f2bf(float f) {
  union { float f; uint32_t u; } v; v.f = f;
  uint32_t r = v.u + 0x7fffu + ((v.u >> 16) & 1u);
  return (u16)(r >> 16);
}

__device__ __forceinline__ float fastexp2(float x) {
  float r;
  asm volatile("v_exp_f32 %0, %1" : "=v"(r) : "v"(x));
  return r;
}

__device__ __forceinline__ u32 cvtpk(float lo, float hi) {
  u32 r;
  asm volatile("v_cvt_pk_bf16_f32 %0, %1, %2" : "=v"(r) : "v"(lo), "v"(hi));
  return r;
}

__device__ __forceinline__ void async16(const void* g, void* l) {
  __builtin_amdgcn_global_load_lds((const __attribute__((address_space(1))) void*)g,
                                   (__attribute__((address_space(3))) void*)l,
                                   16, 0, 0);
}

// raw barrier: does NOT drain vmcnt (unlike __syncthreads)
__device__ __forceinline__ void rawbar() {
  __builtin_amdgcn_s_barrier();
  __builtin_amdgcn_sched_barrier(0);
}

// ---------------- merged prep: x->bf16, w_qkv^T->bf16, w_proj^T->bf16 ----------------
__global__ __launch_bounds__(256) void prep(const float* __restrict__ x,
                                            const float* __restrict__ wq,
                                            const float* __restrict__ wp,
                                            u16* __restrict__ xb,
                                            u16* __restrict__ wqkvT,
                                            u16* __restrict__ wprojT) {
  const int bid = blockIdx.x, tid = threadIdx.x;
  if (bid < 4096) {
    int i = bid * 256 + tid;
    float4 v = ((const float4*)x)[i];
    ushort4 o;
    o.x = f2bf(v.x); o.y = f2bf(v.y); o.z = f2bf(v.z); o.w = f2bf(v.w);
    ((ushort4*)xb)[i] = o;
    return;
  }
  __shared__ float tile[32][33];
  const float* in; u16* outp; int C, bx, by;
  if (bid < 4096 + 3072) {
    int bb = bid - 4096; in = wq; outp = wqkvT; C = 3072; bx = bb % 96; by = bb / 96;
  } else {
    int bb = bid - 7168; in = wp; outp = wprojT; C = 1024; bx = bb % 32; by = bb / 32;
  }
  const int tx = tid & 31, ty = tid >> 5;
  const int c0 = bx * 32, r0 = by * 32;
#pragma unroll
  for (int i = 0; i < 4; i++)
    tile[ty + i * 8][tx] = in[(size_t)(r0 + ty + i * 8) * C + c0 + tx];
  __syncthreads();
#pragma unroll
  for (int i = 0; i < 4; i++)
    outp[(size_t)(c0 + ty + i * 8) * D_MODEL + r0 + tx] = f2bf(tile[tx][ty + i * 8]);
}

// ---------------- BK=32 high-occupancy GEMM (QKV): 128x128 tile, 32KB LDS ----------
// r15's 2-phase discipline but BK=32 double-buffer -> 32KB LDS -> all 3 blocks/CU
// co-resident (launch_bounds(256,4)), 3 waves/SIMD TLP covers vmcnt stalls.
// vmcnt(4)/step (4 loads/step/thread). 64B-pitch swizzle: byte ^= ((row&3)<<4).
// VFUSE: bn>=16 (V third, NBN=24) writes transposed into vT.
template <int F32OUT, int VFUSE, int NBN>
__global__ __launch_bounds__(256, 4) void gemm128k32(const u16* __restrict__ A,
                                                     const u16* __restrict__ BT,
                                                     void* __restrict__ Cout,
                                                     u16* __restrict__ vTout,
                                                     int N) {
  __shared__ u16 As[2][128 * 32];
  __shared__ u16 Bs[2][128 * 32];
  const int tid = threadIdx.x;
  const int lane = tid & 63, w = tid >> 6;
  const int l15 = lane & 15, g = lane >> 4;
  const int wr = w >> 1, wc = w & 1;
  const int id = blockIdx.x;
  const int cid = id >> 3;
  const int bm = (id & 7) * 4 + cid / NBN;
  const int bn = cid % NBN;
  const int K = 1024;
  const u16* Ab = A + (size_t)bm * 128 * K;
  const u16* Bb = BT + (size_t)bn * 128 * K;
  f32x4 acc[4][4];
#pragma unroll
  for (int i = 0; i < 4; i++)
#pragma unroll
    for (int j = 0; j < 4; j++) acc[i][j] = (f32x4){0.f, 0.f, 0.f, 0.f};

  // stage one 128x32 buffer (8KB = 2 chunks/thread); linear dest, inv-swizzled src
#define LD32(dst, srcb, kt_)                                                 \
  do {                                                                       \
    _Pragma("unroll") for (int i_ = 0; i_ < 2; i_++) {                       \
      int o_ = (tid + i_ * 256) * 16;                                        \
      int lo_ = o_ ^ (((o_ >> 6) & 3) << 4);                                 \
      async16((srcb) + (size_t)(lo_ >> 6) * K + (kt_) + ((lo_ & 63) >> 1),   \
              (char*)(dst) + o_);                                            \
    }                                                                        \
  } while (0)

  LD32(As[0], Ab, 0);
  LD32(Bs[0], Bb, 0);
  int cur = 0;
  for (int t = 0; t < 32; t++) {
    if (t < 31) {
      LD32(As[cur ^ 1], Ab, (t + 1) * 32);
      LD32(Bs[cur ^ 1], Bb, (t + 1) * 32);
      asm volatile("s_waitcnt vmcnt(4)" ::: "memory");  // drain step t, keep t+1 flying
    } else {
      asm volatile("s_waitcnt vmcnt(0)" ::: "memory");
    }
    rawbar();
    s16x8 af[4], bf[4];
#pragma unroll
    for (int i = 0; i < 4; i++) {
      int r_ = wr * 64 + i * 16 + l15;
      af[i] = *(const s16x8*)((const char*)As[cur] +
                              ((r_ * 64 + g * 16) ^ ((r_ & 3) << 4)));
    }
#pragma unroll
    for (int jn = 0; jn < 4; jn++) {
      int n_ = wc * 64 + jn * 16 + l15;
      bf[jn] = *(const s16x8*)((const char*)Bs[cur] +
                               ((n_ * 64 + g * 16) ^ ((n_ & 3) << 4)));
    }
    __builtin_amdgcn_s_setprio(1);
#pragma unroll
    for (int i = 0; i < 4; i++)
#pragma unroll
      for (int jn = 0; jn < 4; jn++)
        acc[i][jn] = __builtin_amdgcn_mfma_f32_16x16x32_bf16(af[i], bf[jn], acc[i][jn], 0, 0, 0);
    __builtin_amdgcn_s_setprio(0);
    rawbar();
    cur ^= 1;
  }

  if (VFUSE && bn >= 16) {
#pragma unroll
    for (int i = 0; i < 4; i++) {
      const int m = bm * 128 + wr * 64 + i * 16 + g * 4;
      const int bloc = m >> 11;
      const int tl = m & 2047;
#pragma unroll
      for (int jn = 0; jn < 4; jn++) {
        const int hh = bn * 128 + wc * 64 + jn * 16 + l15 - 2048;
        uint2 pk;
        pk.x = cvtpk(acc[i][jn][0], acc[i][jn][1]);
        pk.y = cvtpk(acc[i][jn][2], acc[i][jn][3]);
        *(uint2*)&vTout[(size_t)(bloc * 1024 + hh) * T_SEQ + tl] = pk;
      }
    }
    return;
  }
#pragma unroll
  for (int i = 0; i < 4; i++) {
    const int row0 = bm * 128 + wr * 64 + i * 16 + g * 4;
#pragma unroll
    for (int jn = 0; jn < 4; jn++) {
      const int col = bn * 128 + wc * 64 + jn * 16 + l15;
#pragma unroll
      for (int r = 0; r < 4; r++) {
        if (F32OUT)
          ((float*)Cout)[(size_t)(row0 + r) * N + col] = acc[i][jn][r];
        else
          ((u16*)Cout)[(size_t)(row0 + r) * N + col] = f2bf(acc[i][jn][r]);
      }
    }
  }
}

// ---------------- r15 BK=64 2-phase GEMM (proj): 128x128, 64KB LDS ----------------
template <int F32OUT, int VFUSE, int NBN>
__global__ __launch_bounds__(256, 2) void gemm128(const u16* __restrict__ A,
                                                  const u16* __restrict__ BT,
                                                  void* __restrict__ Cout,
                                                  u16* __restrict__ vTout,
                                                  int N) {
  __shared__ u16 As[2][128 * 64];
  __shared__ u16 Bs[2][128 * 64];
  const int tid = threadIdx.x;
  const int lane = tid & 63, w = tid >> 6;
  const int l15 = lane & 15, g = lane >> 4;
  const int wr = w >> 1, wc = w & 1;
  const int id = blockIdx.x;
  const int cid = id >> 3;
  const int bm = (id & 7) * 4 + cid / NBN;
  const int bn = cid % NBN;
  const int K = 1024;
  const u16* Ab = A + (size_t)bm * 128 * K;
  const u16* Bb = BT + (size_t)bn * 128 * K;
  f32x4 acc[4][4];
#pragma unroll
  for (int i = 0; i < 4; i++)
#pragma unroll
    for (int j = 0; j < 4; j++) acc[i][j] = (f32x4){0.f, 0.f, 0.f, 0.f};

#define G1_LD(dst, srcb, kt_)                                                \
  do {                                                                       \
    _Pragma("unroll") for (int i_ = 0; i_ < 4; i_++) {                       \
      int o_ = (tid + i_ * 256) * 16;                                        \
      int lo_ = o_ ^ (((o_ >> 7) & 7) << 4);                                 \
      async16((srcb) + (size_t)(lo_ >> 7) * K + (kt_) + ((lo_ & 127) >> 1),  \
              (char*)(dst) + o_);                                            \
    }                                                                        \
  } while (0)

  G1_LD(As[0], Ab, 0);
  G1_LD(Bs[0], Bb, 0);
  int cur = 0;
  for (int t = 0; t < 16; t++) {
    if (t < 15) {
      G1_LD(As[cur ^ 1], Ab, (t + 1) * 64);
      G1_LD(Bs[cur ^ 1], Bb, (t + 1) * 64);
      asm volatile("s_waitcnt vmcnt(8)" ::: "memory");  // drain tile t, keep t+1 flying
    } else {
      asm volatile("s_waitcnt vmcnt(0)" ::: "memory");
    }
    rawbar();
    s16x8 af[4][2], bf[4][2];
#pragma unroll
    for (int i = 0; i < 4; i++) {
      int r_ = wr * 64 + i * 16 + l15;
#pragma unroll
      for (int kk = 0; kk < 2; kk++)
        af[i][kk] = *(const s16x8*)((const char*)As[cur] +
                                    ((r_ * 128 + kk * 64 + g * 16) ^ ((r_ & 7) << 4)));
    }
#pragma unroll
    for (int jn = 0; jn < 4; jn++) {
      int n_ = wc * 64 + jn * 16 + l15;
#pragma unroll
      for (int kk = 0; kk < 2; kk++)
        bf[jn][kk] = *(const s16x8*)((const char*)Bs[cur] +
                                     ((n_ * 128 + kk * 64 + g * 16) ^ ((n_ & 7) << 4)));
    }
    __builtin_amdgcn_s_setprio(1);
#pragma unroll
    for (int i = 0; i < 4; i++)
#pragma unroll
      for (int jn = 0; jn < 4; jn++) {
        acc[i][jn] = __builtin_amdgcn_mfma_f32_16x16x32_bf16(af[i][0], bf[jn][0], acc[i][jn], 0, 0, 0);
        acc[i][jn] = __builtin_amdgcn_mfma_f32_16x16x32_bf16(af[i][1], bf[jn][1], acc[i][jn], 0, 0, 0);
      }
    __builtin_amdgcn_s_setprio(0);
    rawbar();
    cur ^= 1;
  }

  if (VFUSE && bn >= 16) {
#pragma unroll
    for (int i = 0; i < 4; i++) {
      const int m = bm * 128 + wr * 64 + i * 16 + g * 4;
      const int bloc = m >> 11;
      const int tl = m & 2047;
#pragma unroll
      for (int jn = 0; jn < 4; jn++) {
        const int hh = bn * 128 + wc * 64 + jn * 16 + l15 - 2048;
        uint2 pk;
        pk.x = cvtpk(acc[i][jn][0], acc[i][jn][1]);
        pk.y = cvtpk(acc[i][jn][2], acc[i][jn][3]);
        *(uint2*)&vTout[(size_t)(bloc * 1024 + hh) * T_SEQ + tl] = pk;
      }
    }
    return;
  }
#pragma unroll
  for (int i = 0; i < 4; i++) {
    const int row0 = bm * 128 + wr * 64 + i * 16 + g * 4;
#pragma unroll
    for (int jn = 0; jn < 4; jn++) {
      const int col = bn * 128 + wc * 64 + jn * 16 + l15;
#pragma unroll
      for (int r = 0; r < 4; r++) {
        if (F32OUT)
          ((float*)Cout)[(size_t)(row0 + r) * N + col] = acc[i][jn][r];
        else
          ((u16*)Cout)[(size_t)(row0 + r) * N + col] = f2bf(acc[i][jn][r]);
      }
    }
  }
}

// ---------------- causal flash attention v12 (unchanged from r15) ----------
__global__ __launch_bounds__(256, 4) void flash_attn(const u16* __restrict__ qkv,
                                                     const u16* __restrict__ vT,
                                                     u16* __restrict__ attn) {
  __shared__ u16 Ks[2][64 * 64];  // [key][hd], XOR-swizzled
  __shared__ u16 Vs[2][64 * 64];  // [hd][key], XOR-swizzled
  const int tid = threadIdx.x;
  const int lane = tid & 63, w = tid >> 6;
  const int l15 = lane & 15, g = lane >> 4;
  const int id = blockIdx.x;
  const int bh = ((id & 7) << 2) | ((id >> 3) & 3);  // 4 heads per XCD
  const int j = (id >> 5) & 7, k4 = (id >> 8) & 3;   // balanced strip map
  const int qs = (k4 == 0) ? (31 - j) : (k4 == 1) ? (16 + j) : (k4 == 2) ? (15 - j) : j;
  const int b = bh >> 4, h = bh & 15;

  const size_t qrow = (size_t)(b * T_SEQ + qs * 64 + w * 16 + l15);
  s16x8 qf[2];
  qf[0] = *(const s16x8*)(qkv + qrow * QKV_P + h * HDIM + 0 * 32 + g * 8);
  qf[1] = *(const s16x8*)(qkv + qrow * QKV_P + h * HDIM + 1 * 32 + g * 8);

  f32x4 O[4];
#pragma unroll
  for (int t = 0; t < 4; t++) O[t] = (f32x4){0.f, 0.f, 0.f, 0.f};
  f32x4 sumacc = (f32x4){0.f, 0.f, 0.f, 0.f};  // l via ones-row PV MFMA
  float m_s = -1e30f;
  const int qrl = w * 16 + l15;
  const float sc = 0.18033688011112042f;  // (1/sqrt(64)) * log2(e)
  const s16x4 onesf = {(short)0x3F80, (short)0x3F80, (short)0x3F80, (short)0x3F80};

#define STAGE(buf, kvt_)                                                                     \
  do {                                                                                       \
    _Pragma("unroll") for (int i_ = 0; i_ < 2; i_++) {                                       \
      int o_ = (tid + i_ * 256) * 16;                                                        \
      int lo_ = o_ ^ (((o_ >> 7) & 7) << 4);                                                 \
      int row_ = lo_ >> 7;                                                                   \
      int byt_ = lo_ & 127;                                                                  \
      async16(qkv + (size_t)(b * T_SEQ + (kvt_) * 64 + row_) * QKV_P + D_MODEL + h * HDIM +  \
                  (byt_ >> 1),                                                               \
              (char*)Ks[buf] + o_);                                                          \
      async16(vT + (size_t)(bh * HDIM + row_) * T_SEQ + (kvt_) * 64 + (byt_ >> 1),           \
              (char*)Vs[buf] + o_);                                                          \
    }                                                                                        \
  } while (0)

  STAGE(0, 0);
  int cur = 0;
  const int nt = qs + 1;
  for (int kvt = 0; kvt < nt; ++kvt) {
    if (kvt < qs) {
      STAGE(cur ^ 1, kvt + 1);
      asm volatile("s_waitcnt vmcnt(4)" ::: "memory");
    } else {
      asm volatile("s_waitcnt vmcnt(0)" ::: "memory");
    }
    rawbar();

    f32x4 S[4];
#pragma unroll
    for (int t16 = 0; t16 < 4; t16++) S[t16] = (f32x4){0.f, 0.f, 0.f, 0.f};
#pragma unroll
    for (int t16 = 0; t16 < 4; t16++)
#pragma unroll
      for (int kk = 0; kk < 2; kk++) {
        int key = t16 * 16 + l15;
        int bp = (key * 128 + kk * 64 + g * 16) ^ ((key & 7) << 4);
        s16x8 kf = *(const s16x8*)((const char*)Ks[cur] + bp);
        S[t16] = __builtin_amdgcn_mfma_f32_16x16x32_bf16(kf, qf[kk], S[t16], 0, 0, 0);
      }

    if (kvt == qs) {  // causal mask (raw units)
#pragma unroll
      for (int t16 = 0; t16 < 4; t16++)
#pragma unroll
        for (int r = 0; r < 4; r++)
          if (t16 * 16 + g * 4 + r > qrl) S[t16][r] = -3e38f;
    }
    // per-lane PARTIAL max (this lane's 16 of the query's 64 keys) — no shfl
    float pmx = fmaxf(fmaxf(fmaxf(S[0][0], S[0][1]), fmaxf(S[0][2], S[0][3])),
                      fmaxf(fmaxf(S[1][0], S[1][1]), fmaxf(S[1][2], S[1][3])));
    pmx = fmaxf(pmx, fmaxf(fmaxf(fmaxf(S[2][0], S[2][1]), fmaxf(S[2][2], S[2][3])),
                           fmaxf(fmaxf(S[3][0], S[3][1]), fmaxf(S[3][2], S[3][3]))));
    // __all over wave == testing full row max for every query in this wave
    if (!__all(pmx - m_s <= 40.f)) {  // rare rescale path
      float mx = fmaxf(pmx, __shfl_xor(pmx, 16));
      mx = fmaxf(mx, __shfl_xor(mx, 32));
      const float mnew = fmaxf(m_s, mx);
      const float alpha = fastexp2((m_s - mnew) * sc);
      m_s = mnew;
      sumacc[0] *= alpha; sumacc[1] *= alpha; sumacc[2] *= alpha; sumacc[3] *= alpha;
#pragma unroll
      for (int t = 0; t < 4; t++)
#pragma unroll
        for (int r = 0; r < 4; r++) O[t][r] *= alpha;
    }
    const float msc = m_s * sc;
    float p[16];
#pragma unroll
    for (int t16 = 0; t16 < 4; t16++)
#pragma unroll
      for (int r = 0; r < 4; r++) p[t16 * 4 + r] = fastexp2(fmaf(S[t16][r], sc, -msc));

    // pack + PV (16x16x16: B-frag k = g*4+j == S/P C-layout) + ones-row sum MFMA
#pragma unroll
    for (int t16 = 0; t16 < 4; t16++) {
      union { u32 u[2]; s16x4 v; } pbv;
      pbv.u[0] = cvtpk(p[t16 * 4 + 0], p[t16 * 4 + 1]);
      pbv.u[1] = cvtpk(p[t16 * 4 + 2], p[t16 * 4 + 3]);
      sumacc = __builtin_amdgcn_mfma_f32_16x16x16bf16_1k(onesf, pbv.v, sumacc, 0, 0, 0);
#pragma unroll
      for (int t = 0; t < 4; t++) {
        int hd = t * 16 + l15;
        int bp = (hd * 128 + t16 * 32 + g * 8) ^ ((hd & 7) << 4);
        s16x4 vf = *(const s16x4*)((const char*)Vs[cur] + bp);
        O[t] = __builtin_amdgcn_mfma_f32_16x16x16bf16_1k(vf, pbv.v, O[t], 0, 0, 0);
      }
    }
    rawbar();
    cur ^= 1;
  }

  const float inv = 1.0f / sumacc[0];
  const size_t row = (size_t)(b * T_SEQ + qs * 64 + w * 16 + l15);
#pragma unroll
  for (int t = 0; t < 4; t++)
#pragma unroll
    for (int pr = 0; pr < 2; pr++) {
      u32 pk = cvtpk(O[t][pr * 2 + 0] * inv, O[t][pr * 2 + 1] * inv);
      *(u32*)&attn[row * D_MODEL + h * HDIM + t * 16 + g * 4 + pr * 2] = pk;
    }
}

extern "C" void kernel_launch(void* const* d_in, const int* in_sizes, int n_in,
                              void* d_out, int out_size, void* d_ws, size_t ws_size,
                              hipStream_t stream) {
  const float* x = (const float*)d_in[0];
  const float* w_qkv = (const float*)d_in[1];
  const float* w_proj = (const float*)d_in[2];
  float* out = (float*)d_out;
  char* ws = (char*)d_ws;
  const size_t MB = (size_t)1 << 20;
  if (ws_size < 56 * MB) return;  // need 56 MB scratch
  u16* xb = (u16*)(ws + 0);            // 8 MB  [4096][1024] bf16
  u16* wqkvT = (u16*)(ws + 8 * MB);    // 6 MB  [3072][1024] bf16
  u16* wprojT = (u16*)(ws + 14 * MB);  // 2 MB  [1024][1024] bf16
  u16* qkv = (u16*)(ws + 16 * MB);     // 24 MB [4096][3072] bf16 (V third unused)
  u16* vT = (u16*)(ws + 40 * MB);      // 8 MB  [2*1024][2048] bf16
  u16* attn = (u16*)(ws + 48 * MB);    // 8 MB  [4096][1024] bf16

  prep<<<8192, 256, 0, stream>>>(x, w_qkv, w_proj, xb, wqkvT, wprojT);
  gemm128k32<0, 1, 24><<<768, 256, 0, stream>>>(xb, wqkvT, qkv, vT, QKV_P);
  flash_attn<<<1024, 256, 0, stream>>>(qkv, vT, attn);
  gemm128<1, 0, 8><<<256, 256, 0, stream>>>(attn, wprojT, out, nullptr, D_MODEL);
}

// Round 20
// 102.375 us; speedup vs baseline: 1.3288x; 1.0033x over previous
//
#include <hip/hip_runtime.h>
#include <stdint.h>

#define B_SZ 2
#define T_SEQ 2048
#define D_MODEL 1024
#define NHEADS 16
#define HDIM 64
#define QKV_P (3 * D_MODEL) /* 3072 */

typedef unsigned short u16;
typedef uint32_t u32;
typedef __attribute__((ext_vector_type(4))) float f32x4;
typedef __attribute__((ext_vector_type(8))) short s16x8;
typedef __attribute__((ext_vector_type(4))) short s16x4;

__device__ __forceinline__ u16 f2bf(float f) {
  union { float f; uint32_t u; } v; v.f = f;
  uint32_t r = v.u + 0x7fffu + ((v.u >> 16) & 1u);
  return (u16)(r >> 16);
}

__device__ __forceinline__ float fastexp2(float x) {
  float r;
  asm volatile("v_exp_f32 %0, %1" : "=v"(r) : "v"(x));
  return r;
}

__device__ __forceinline__ u32 cvtpk(float lo, float hi) {
  u32 r;
  asm volatile("v_cvt_pk_bf16_f32 %0, %1, %2" : "=v"(r) : "v"(lo), "v"(hi));
  return r;
}

__device__ __forceinline__ void async16(const void* g, void* l) {
  __builtin_amdgcn_global_load_lds((const __attribute__((address_space(1))) void*)g,
                                   (__attribute__((address_space(3))) void*)l,
                                   16, 0, 0);
}

// raw barrier: does NOT drain vmcnt (unlike __syncthreads)
__device__ __forceinline__ void rawbar() {
  __builtin_amdgcn_s_barrier();
  __builtin_amdgcn_sched_barrier(0);
}

// ---------------- merged prep: x->bf16, w_qkv^T->bf16, w_proj^T->bf16 ----------------
__global__ __launch_bounds__(256) void prep(const float* __restrict__ x,
                                            const float* __restrict__ wq,
                                            const float* __restrict__ wp,
                                            u16* __restrict__ xb,
                                            u16* __restrict__ wqkvT,
                                            u16* __restrict__ wprojT) {
  const int bid = blockIdx.x, tid = threadIdx.x;
  if (bid < 4096) {
    int i = bid * 256 + tid;
    float4 v = ((const float4*)x)[i];
    ushort4 o;
    o.x = f2bf(v.x); o.y = f2bf(v.y); o.z = f2bf(v.z); o.w = f2bf(v.w);
    ((ushort4*)xb)[i] = o;
    return;
  }
  __shared__ float tile[32][33];
  const float* in; u16* outp; int C, bx, by;
  if (bid < 4096 + 3072) {
    int bb = bid - 4096; in = wq; outp = wqkvT; C = 3072; bx = bb % 96; by = bb / 96;
  } else {
    int bb = bid - 7168; in = wp; outp = wprojT; C = 1024; bx = bb % 32; by = bb / 32;
  }
  const int tx = tid & 31, ty = tid >> 5;
  const int c0 = bx * 32, r0 = by * 32;
#pragma unroll
  for (int i = 0; i < 4; i++)
    tile[ty + i * 8][tx] = in[(size_t)(r0 + ty + i * 8) * C + c0 + tx];
  __syncthreads();
#pragma unroll
  for (int i = 0; i < 4; i++)
    outp[(size_t)(c0 + ty + i * 8) * D_MODEL + r0 + tx] = f2bf(tile[tx][ty + i * 8]);
}

// ---------------- BK=32 high-occupancy GEMM (QKV): 128x128 tile, 32KB LDS ----------
template <int F32OUT, int VFUSE, int NBN>
__global__ __launch_bounds__(256, 4) void gemm128k32(const u16* __restrict__ A,
                                                     const u16* __restrict__ BT,
                                                     void* __restrict__ Cout,
                                                     u16* __restrict__ vTout,
                                                     int N) {
  __shared__ u16 As[2][128 * 32];
  __shared__ u16 Bs[2][128 * 32];
  const int tid = threadIdx.x;
  const int lane = tid & 63, w = tid >> 6;
  const int l15 = lane & 15, g = lane >> 4;
  const int wr = w >> 1, wc = w & 1;
  const int id = blockIdx.x;
  const int cid = id >> 3;
  const int bm = (id & 7) * 4 + cid / NBN;
  const int bn = cid % NBN;
  const int K = 1024;
  const u16* Ab = A + (size_t)bm * 128 * K;
  const u16* Bb = BT + (size_t)bn * 128 * K;
  f32x4 acc[4][4];
#pragma unroll
  for (int i = 0; i < 4; i++)
#pragma unroll
    for (int j = 0; j < 4; j++) acc[i][j] = (f32x4){0.f, 0.f, 0.f, 0.f};

#define LD32(dst, srcb, kt_)                                                 \
  do {                                                                       \
    _Pragma("unroll") for (int i_ = 0; i_ < 2; i_++) {                       \
      int o_ = (tid + i_ * 256) * 16;                                        \
      int lo_ = o_ ^ (((o_ >> 6) & 3) << 4);                                 \
      async16((srcb) + (size_t)(lo_ >> 6) * K + (kt_) + ((lo_ & 63) >> 1),   \
              (char*)(dst) + o_);                                            \
    }                                                                        \
  } while (0)

  LD32(As[0], Ab, 0);
  LD32(Bs[0], Bb, 0);
  int cur = 0;
  for (int t = 0; t < 32; t++) {
    if (t < 31) {
      LD32(As[cur ^ 1], Ab, (t + 1) * 32);
      LD32(Bs[cur ^ 1], Bb, (t + 1) * 32);
      asm volatile("s_waitcnt vmcnt(4)" ::: "memory");
    } else {
      asm volatile("s_waitcnt vmcnt(0)" ::: "memory");
    }
    rawbar();
    s16x8 af[4], bf[4];
#pragma unroll
    for (int i = 0; i < 4; i++) {
      int r_ = wr * 64 + i * 16 + l15;
      af[i] = *(const s16x8*)((const char*)As[cur] +
                              ((r_ * 64 + g * 16) ^ ((r_ & 3) << 4)));
    }
#pragma unroll
    for (int jn = 0; jn < 4; jn++) {
      int n_ = wc * 64 + jn * 16 + l15;
      bf[jn] = *(const s16x8*)((const char*)Bs[cur] +
                               ((n_ * 64 + g * 16) ^ ((n_ & 3) << 4)));
    }
    __builtin_amdgcn_s_setprio(1);
#pragma unroll
    for (int i = 0; i < 4; i++)
#pragma unroll
      for (int jn = 0; jn < 4; jn++)
        acc[i][jn] = __builtin_amdgcn_mfma_f32_16x16x32_bf16(af[i], bf[jn], acc[i][jn], 0, 0, 0);
    __builtin_amdgcn_s_setprio(0);
    rawbar();
    cur ^= 1;
  }

  if (VFUSE && bn >= 16) {
#pragma unroll
    for (int i = 0; i < 4; i++) {
      const int m = bm * 128 + wr * 64 + i * 16 + g * 4;
      const int bloc = m >> 11;
      const int tl = m & 2047;
#pragma unroll
      for (int jn = 0; jn < 4; jn++) {
        const int hh = bn * 128 + wc * 64 + jn * 16 + l15 - 2048;
        uint2 pk;
        pk.x = cvtpk(acc[i][jn][0], acc[i][jn][1]);
        pk.y = cvtpk(acc[i][jn][2], acc[i][jn][3]);
        *(uint2*)&vTout[(size_t)(bloc * 1024 + hh) * T_SEQ + tl] = pk;
      }
    }
    return;
  }
#pragma unroll
  for (int i = 0; i < 4; i++) {
    const int row0 = bm * 128 + wr * 64 + i * 16 + g * 4;
#pragma unroll
    for (int jn = 0; jn < 4; jn++) {
      const int col = bn * 128 + wc * 64 + jn * 16 + l15;
#pragma unroll
      for (int r = 0; r < 4; r++) {
        if (F32OUT)
          ((float*)Cout)[(size_t)(row0 + r) * N + col] = acc[i][jn][r];
        else
          ((u16*)Cout)[(size_t)(row0 + r) * N + col] = f2bf(acc[i][jn][r]);
      }
    }
  }
}

// ---------------- r15 BK=64 2-phase GEMM (proj): 128x128, 64KB LDS ----------------
template <int F32OUT, int VFUSE, int NBN>
__global__ __launch_bounds__(256, 2) void gemm128(const u16* __restrict__ A,
                                                  const u16* __restrict__ BT,
                                                  void* __restrict__ Cout,
                                                  u16* __restrict__ vTout,
                                                  int N) {
  __shared__ u16 As[2][128 * 64];
  __shared__ u16 Bs[2][128 * 64];
  const int tid = threadIdx.x;
  const int lane = tid & 63, w = tid >> 6;
  const int l15 = lane & 15, g = lane >> 4;
  const int wr = w >> 1, wc = w & 1;
  const int id = blockIdx.x;
  const int cid = id >> 3;
  const int bm = (id & 7) * 4 + cid / NBN;
  const int bn = cid % NBN;
  const int K = 1024;
  const u16* Ab = A + (size_t)bm * 128 * K;
  const u16* Bb = BT + (size_t)bn * 128 * K;
  f32x4 acc[4][4];
#pragma unroll
  for (int i = 0; i < 4; i++)
#pragma unroll
    for (int j = 0; j < 4; j++) acc[i][j] = (f32x4){0.f, 0.f, 0.f, 0.f};

#define G1_LD(dst, srcb, kt_)                                                \
  do {                                                                       \
    _Pragma("unroll") for (int i_ = 0; i_ < 4; i_++) {                       \
      int o_ = (tid + i_ * 256) * 16;                                        \
      int lo_ = o_ ^ (((o_ >> 7) & 7) << 4);                                 \
      async16((srcb) + (size_t)(lo_ >> 7) * K + (kt_) + ((lo_ & 127) >> 1),  \
              (char*)(dst) + o_);                                            \
    }                                                                        \
  } while (0)

  G1_LD(As[0], Ab, 0);
  G1_LD(Bs[0], Bb, 0);
  int cur = 0;
  for (int t = 0; t < 16; t++) {
    if (t < 15) {
      G1_LD(As[cur ^ 1], Ab, (t + 1) * 64);
      G1_LD(Bs[cur ^ 1], Bb, (t + 1) * 64);
      asm volatile("s_waitcnt vmcnt(8)" ::: "memory");
    } else {
      asm volatile("s_waitcnt vmcnt(0)" ::: "memory");
    }
    rawbar();
    s16x8 af[4][2], bf[4][2];
#pragma unroll
    for (int i = 0; i < 4; i++) {
      int r_ = wr * 64 + i * 16 + l15;
#pragma unroll
      for (int kk = 0; kk < 2; kk++)
        af[i][kk] = *(const s16x8*)((const char*)As[cur] +
                                    ((r_ * 128 + kk * 64 + g * 16) ^ ((r_ & 7) << 4)));
    }
#pragma unroll
    for (int jn = 0; jn < 4; jn++) {
      int n_ = wc * 64 + jn * 16 + l15;
#pragma unroll
      for (int kk = 0; kk < 2; kk++)
        bf[jn][kk] = *(const s16x8*)((const char*)Bs[cur] +
                                     ((n_ * 128 + kk * 64 + g * 16) ^ ((n_ & 7) << 4)));
    }
    __builtin_amdgcn_s_setprio(1);
#pragma unroll
    for (int i = 0; i < 4; i++)
#pragma unroll
      for (int jn = 0; jn < 4; jn++) {
        acc[i][jn] = __builtin_amdgcn_mfma_f32_16x16x32_bf16(af[i][0], bf[jn][0], acc[i][jn], 0, 0, 0);
        acc[i][jn] = __builtin_amdgcn_mfma_f32_16x16x32_bf16(af[i][1], bf[jn][1], acc[i][jn], 0, 0, 0);
      }
    __builtin_amdgcn_s_setprio(0);
    rawbar();
    cur ^= 1;
  }

  if (VFUSE && bn >= 16) {
#pragma unroll
    for (int i = 0; i < 4; i++) {
      const int m = bm * 128 + wr * 64 + i * 16 + g * 4;
      const int bloc = m >> 11;
      const int tl = m & 2047;
#pragma unroll
      for (int jn = 0; jn < 4; jn++) {
        const int hh = bn * 128 + wc * 64 + jn * 16 + l15 - 2048;
        uint2 pk;
        pk.x = cvtpk(acc[i][jn][0], acc[i][jn][1]);
        pk.y = cvtpk(acc[i][jn][2], acc[i][jn][3]);
        *(uint2*)&vTout[(size_t)(bloc * 1024 + hh) * T_SEQ + tl] = pk;
      }
    }
    return;
  }
#pragma unroll
  for (int i = 0; i < 4; i++) {
    const int row0 = bm * 128 + wr * 64 + i * 16 + g * 4;
#pragma unroll
    for (int jn = 0; jn < 4; jn++) {
      const int col = bn * 128 + wc * 64 + jn * 16 + l15;
#pragma unroll
      for (int r = 0; r < 4; r++) {
        if (F32OUT)
          ((float*)Cout)[(size_t)(row0 + r) * N + col] = acc[i][jn][r];
        else
          ((u16*)Cout)[(size_t)(row0 + r) * N + col] = f2bf(acc[i][jn][r]);
      }
    }
  }
}

// ---------------- causal flash attention v13: in-wave 1-tile pipeline ----------
// Iteration i: QK MFMAs of tile i issue FIRST, then softmax+PV of tile i-1 runs on
// the VALU while they retire (chain/tile ~ max(MFMA,VALU) not sum). Staging split
// K-then-V so vmcnt(2) at tile entry == "K(i) landed, V(i) flying, V(i-1) drained".
// Diagonal (masked) tile handled in epilogue after vmcnt(0).
__global__ __launch_bounds__(256, 4) void flash_attn(const u16* __restrict__ qkv,
                                                     const u16* __restrict__ vT,
                                                     u16* __restrict__ attn) {
  __shared__ u16 Ks[2][64 * 64];  // [key][hd], XOR-swizzled
  __shared__ u16 Vs[2][64 * 64];  // [hd][key], XOR-swizzled
  const int tid = threadIdx.x;
  const int lane = tid & 63, w = tid >> 6;
  const int l15 = lane & 15, g = lane >> 4;
  const int id = blockIdx.x;
  const int bh = ((id & 7) << 2) | ((id >> 3) & 3);  // 4 heads per XCD
  const int j = (id >> 5) & 7, k4 = (id >> 8) & 3;   // balanced strip map
  const int qs = (k4 == 0) ? (31 - j) : (k4 == 1) ? (16 + j) : (k4 == 2) ? (15 - j) : j;
  const int b = bh >> 4, h = bh & 15;

  const size_t qrow = (size_t)(b * T_SEQ + qs * 64 + w * 16 + l15);
  s16x8 qf[2];
  qf[0] = *(const s16x8*)(qkv + qrow * QKV_P + h * HDIM + 0 * 32 + g * 8);
  qf[1] = *(const s16x8*)(qkv + qrow * QKV_P + h * HDIM + 1 * 32 + g * 8);

  f32x4 O[4];
#pragma unroll
  for (int t = 0; t < 4; t++) O[t] = (f32x4){0.f, 0.f, 0.f, 0.f};
  f32x4 sumacc = (f32x4){0.f, 0.f, 0.f, 0.f};  // l via ones-row PV MFMA
  float m_s = -1e30f;
  const int qrl = w * 16 + l15;
  const float sc = 0.18033688011112042f;  // (1/sqrt(64)) * log2(e)
  const s16x4 onesf = {(short)0x3F80, (short)0x3F80, (short)0x3F80, (short)0x3F80};

  // K-loads then V-loads (2 each per thread) so counted vmcnt can split them
#define STAGEK(buf, kvt_)                                                                    \
  do {                                                                                       \
    _Pragma("unroll") for (int i_ = 0; i_ < 2; i_++) {                                       \
      int o_ = (tid + i_ * 256) * 16;                                                        \
      int lo_ = o_ ^ (((o_ >> 7) & 7) << 4);                                                 \
      async16(qkv + (size_t)(b * T_SEQ + (kvt_) * 64 + (lo_ >> 7)) * QKV_P + D_MODEL +       \
                  h * HDIM + ((lo_ & 127) >> 1),                                             \
              (char*)Ks[buf] + o_);                                                          \
    }                                                                                        \
  } while (0)
#define STAGEV(buf, kvt_)                                                                    \
  do {                                                                                       \
    _Pragma("unroll") for (int i_ = 0; i_ < 2; i_++) {                                       \
      int o_ = (tid + i_ * 256) * 16;                                                        \
      int lo_ = o_ ^ (((o_ >> 7) & 7) << 4);                                                 \
      async16(vT + (size_t)(bh * HDIM + (lo_ >> 7)) * T_SEQ + (kvt_) * 64 +                  \
                  ((lo_ & 127) >> 1),                                                        \
              (char*)Vs[buf] + o_);                                                          \
    }                                                                                        \
  } while (0)

  // softmax (defer-max) + PV + ones-sum for tile held in Sx, V in Vs[vb_]
#define SOFTMAX_PV(Sx, vb_)                                                                  \
  {                                                                                          \
    float pmx_ = fmaxf(fmaxf(fmaxf(Sx[0][0], Sx[0][1]), fmaxf(Sx[0][2], Sx[0][3])),          \
                       fmaxf(fmaxf(Sx[1][0], Sx[1][1]), fmaxf(Sx[1][2], Sx[1][3])));         \
    pmx_ = fmaxf(pmx_, fmaxf(fmaxf(fmaxf(Sx[2][0], Sx[2][1]), fmaxf(Sx[2][2], Sx[2][3])),    \
                             fmaxf(fmaxf(Sx[3][0], Sx[3][1]), fmaxf(Sx[3][2], Sx[3][3]))));  \
    if (!__all(pmx_ - m_s <= 40.f)) {                                                        \
      float mx_ = fmaxf(pmx_, __shfl_xor(pmx_, 16));                                         \
      mx_ = fmaxf(mx_, __shfl_xor(mx_, 32));                                                 \
      const float mnew_ = fmaxf(m_s, mx_);                                                   \
      const float alpha_ = fastexp2((m_s - mnew_) * sc);                                     \
      m_s = mnew_;                                                                           \
      sumacc[0] *= alpha_; sumacc[1] *= alpha_; sumacc[2] *= alpha_; sumacc[3] *= alpha_;    \
      _Pragma("unroll") for (int t = 0; t < 4; t++)                                          \
      _Pragma("unroll") for (int r = 0; r < 4; r++) O[t][r] *= alpha_;                       \
    }                                                                                        \
    const float msc_ = m_s * sc;                                                             \
    float p_[16];                                                                            \
    _Pragma("unroll") for (int t16 = 0; t16 < 4; t16++)                                      \
    _Pragma("unroll") for (int r = 0; r < 4; r++)                                            \
        p_[t16 * 4 + r] = fastexp2(fmaf(Sx[t16][r], sc, -msc_));                             \
    _Pragma("unroll") for (int t16 = 0; t16 < 4; t16++) {                                    \
      union { u32 u[2]; s16x4 v; } pbv_;                                                     \
      pbv_.u[0] = cvtpk(p_[t16 * 4 + 0], p_[t16 * 4 + 1]);                                   \
      pbv_.u[1] = cvtpk(p_[t16 * 4 + 2], p_[t16 * 4 + 3]);                                   \
      sumacc = __builtin_amdgcn_mfma_f32_16x16x16bf16_1k(onesf, pbv_.v, sumacc, 0, 0, 0);    \
      _Pragma("unroll") for (int t = 0; t < 4; t++) {                                        \
        int hd_ = t * 16 + l15;                                                              \
        int bp_ = (hd_ * 128 + t16 * 32 + g * 8) ^ ((hd_ & 7) << 4);                         \
        s16x4 vf_ = *(const s16x4*)((const char*)Vs[vb_] + bp_);                             \
        O[t] = __builtin_amdgcn_mfma_f32_16x16x16bf16_1k(vf_, pbv_.v, O[t], 0, 0, 0);        \
      }                                                                                      \
    }                                                                                        \
  }

  STAGEK(0, 0);
  STAGEV(0, 0);
  f32x4 Sp[4];
  const int nt = qs + 1;
  for (int i = 0; i < nt; ++i) {
    // K(i) landed; V(i) still in flight; V(i-1) (issued earlier) drained
    asm volatile("s_waitcnt vmcnt(2)" ::: "memory");
    rawbar();
    f32x4 Sn[4];
#pragma unroll
    for (int t16 = 0; t16 < 4; t16++) Sn[t16] = (f32x4){0.f, 0.f, 0.f, 0.f};
#pragma unroll
    for (int t16 = 0; t16 < 4; t16++)
#pragma unroll
      for (int kk = 0; kk < 2; kk++) {
        int key = t16 * 16 + l15;
        int bp = (key * 128 + kk * 64 + g * 16) ^ ((key & 7) << 4);
        s16x8 kf = *(const s16x8*)((const char*)Ks[i & 1] + bp);
        Sn[t16] = __builtin_amdgcn_mfma_f32_16x16x32_bf16(kf, qf[kk], Sn[t16], 0, 0, 0);
      }
    if (i > 0) {
      SOFTMAX_PV(Sp, (i - 1) & 1);  // VALU work overlaps the in-flight QK MFMAs
    }
    rawbar();
    if (i + 1 < nt) {
      STAGEK((i + 1) & 1, i + 1);
      STAGEV((i + 1) & 1, i + 1);
    }
    Sp[0] = Sn[0]; Sp[1] = Sn[1]; Sp[2] = Sn[2]; Sp[3] = Sn[3];
  }
  // epilogue: diagonal tile nt-1 with causal mask
  asm volatile("s_waitcnt vmcnt(0)" ::: "memory");
  rawbar();
#pragma unroll
  for (int t16 = 0; t16 < 4; t16++)
#pragma unroll
    for (int r = 0; r < 4; r++)
      if (t16 * 16 + g * 4 + r > qrl) Sp[t16][r] = -3e38f;
  SOFTMAX_PV(Sp, (nt - 1) & 1);

  const float inv = 1.0f / sumacc[0];
  const size_t row = (size_t)(b * T_SEQ + qs * 64 + w * 16 + l15);
#pragma unroll
  for (int t = 0; t < 4; t++)
#pragma unroll
    for (int pr = 0; pr < 2; pr++) {
      u32 pk = cvtpk(O[t][pr * 2 + 0] * inv, O[t][pr * 2 + 1] * inv);
      *(u32*)&attn[row * D_MODEL + h * HDIM + t * 16 + g * 4 + pr * 2] = pk;
    }
}

extern "C" void kernel_launch(void* const* d_in, const int* in_sizes, int n_in,
                              void* d_out, int out_size, void* d_ws, size_t ws_size,
                              hipStream_t stream) {
  const float* x = (const float*)d_in[0];
  const float* w_qkv = (const float*)d_in[1];
  const float* w_proj = (const float*)d_in[2];
  float* out = (float*)d_out;
  char* ws = (char*)d_ws;
  const size_t MB = (size_t)1 << 20;
  if (ws_size < 56 * MB) return;  // need 56 MB scratch
  u16* xb = (u16*)(ws + 0);            // 8 MB  [4096][1024] bf16
  u16* wqkvT = (u16*)(ws + 8 * MB);    // 6 MB  [3072][1024] bf16
  u16* wprojT = (u16*)(ws + 14 * MB);  // 2 MB  [1024][1024] bf16
  u16* qkv = (u16*)(ws + 16 * MB);     // 24 MB [4096][3072] bf16 (V third unused)
  u16* vT = (u16*)(ws + 40 * MB);      // 8 MB  [2*1024][2048] bf16
  u16* attn = (u16*)(ws + 48 * MB);    // 8 MB  [4096][1024] bf16

  prep<<<8192, 256, 0, stream>>>(x, w_qkv, w_proj, xb, wqkvT, wprojT);
  gemm128k32<0, 1, 24><<<768, 256, 0, stream>>>(xb, wqkvT, qkv, vT, QKV_P);
  flash_attn<<<1024, 256, 0, stream>>>(qkv, vT, attn);
  gemm128<1, 0, 8><<<256, 256, 0, stream>>>(attn, wprojT, out, nullptr, D_MODEL);
}